// Round 3
// baseline (1815.177 us; speedup 1.0000x reference)
//
#include <hip/hip_runtime.h>
#include <math.h>

#define N_PROP 1024
#define C_FEAT 32
#define ROI 7
#define SR 6
#define S_GRID 42
#define IMG_H 360
#define IMG_W 1200
#define BEV_H 700
#define BEV_W 800
#define D_FEAT (C_FEAT*ROI*ROI)   // 1568
#define HID 2048
#define NMS_K 100
#define NMS_THR 0.01f

// ---------------- workspace layout (float offsets) ----------------
// Regions A/B/C are 2M floats each. Lifetimes:
//   roi:      img_s -> A, bev_s -> B
//   gemm1:    reads A,B -> writes h1 -> C
//   gemm2sk:  reads C   -> writes P (2x 2M partials) -> A+B (img_s/bev_s dead)
//   combine2: reads A+B -> writes h2 -> C (h1 dead)
// Total ~25.3 MB (< proven 29 MB footprint).
#define WS_IMG_BOXES 0
#define WS_BEV_BOXES (WS_IMG_BOXES + 4*N_PROP)
#define WS_OBJS      (WS_BEV_BOXES + 4*N_PROP)
#define WS_OFF       (WS_OBJS + 2*N_PROP)
#define WS_ORIENT    (WS_OFF + 10*N_PROP)
#define WS_PRED      (WS_ORIENT + N_PROP)
#define WS_PBEV      (WS_PRED + 6*N_PROP)
#define WS_SCORES    (WS_PBEV + 4*N_PROP)
#define WS_IDX       (WS_SCORES + N_PROP)   // ints (100)
#define WS_A         40960
#define WS_B         (WS_A + N_PROP*HID)
#define WS_C         (WS_B + N_PROP*HID)

// ---------------- K1: project boxes ----------------
__global__ void boxes_kernel(const float* __restrict__ anchors,
                             const float* __restrict__ calib,
                             const int* __restrict__ imshape,
                             float* __restrict__ img_boxes,
                             float* __restrict__ bev_boxes) {
    int n = blockIdx.x * blockDim.x + threadIdx.x;
    if (n >= N_PROP) return;
    float x = anchors[n*6+0], y = anchors[n*6+1], z = anchors[n*6+2];
    float dx = anchors[n*6+3], dy = anchors[n*6+4], dz = anchors[n*6+5];

    bev_boxes[n*4+0] = ((x - dx*0.5f) - (-40.0f)) / 0.1f;
    bev_boxes[n*4+1] = (70.0f - (z + dz*0.5f)) / 0.1f;
    bev_boxes[n*4+2] = ((x + dx*0.5f) - (-40.0f)) / 0.1f;
    bev_boxes[n*4+3] = (70.0f - (z - dz*0.5f)) / 0.1f;

    float P[12];
    #pragma unroll
    for (int i = 0; i < 12; i++) P[i] = calib[i];

    float umin = 1e30f, vmin = 1e30f, umax = -1e30f, vmax = -1e30f;
    #pragma unroll
    for (int k = 0; k < 8; k++) {
        float fsx = (k & 4) ? 1.0f : -1.0f;
        float fsy = (k & 2) ? 1.0f : -1.0f;
        float fsz = (k & 1) ? 1.0f : -1.0f;
        float cx = x + fsx * dx * 0.5f;
        float cy = y + fsy * dy * 0.5f;
        float cz = z + fsz * dz * 0.5f;
        float p0 = P[0]*cx + P[1]*cy + P[2]*cz + P[3];
        float p1 = P[4]*cx + P[5]*cy + P[6]*cz + P[7];
        float p2 = P[8]*cx + P[9]*cy + P[10]*cz + P[11];
        float zz = fmaxf(p2, 0.1f);
        float u = p0 / zz, v = p1 / zz;
        umin = fminf(umin, u); umax = fmaxf(umax, u);
        vmin = fminf(vmin, v); vmax = fmaxf(vmax, v);
    }
    float Hf = (float)imshape[0];
    float Wf = (float)imshape[1];
    img_boxes[n*4+0] = fminf(fmaxf(umin, 0.0f), Wf);
    img_boxes[n*4+1] = fminf(fmaxf(vmin, 0.0f), Hf);
    img_boxes[n*4+2] = fminf(fmaxf(umax, 0.0f), Wf);
    img_boxes[n*4+3] = fminf(fmaxf(vmax, 0.0f), Hf);
}

// ---------------- K2: roi_align, one block per (box, map), channel loop ----------
// Geometry computed ONCE per block; per-lane sums accumulated over the 6 sub-rows,
// segmented-6 shuffle reduce only once per output row (was once per sub-row).
__global__ __launch_bounds__(64) void roi_map_kernel(
        const float* __restrict__ imgF, const float* __restrict__ bevF,
        const float* __restrict__ img_boxes, const float* __restrict__ bev_boxes,
        float* __restrict__ img_out, float* __restrict__ bev_out) {
    int b = blockIdx.x;      // box 0..1023
    int mapid = blockIdx.y;  // 0=img, 1=bev

    const float* F; const float* boxes; float* outp; int W, H;
    if (mapid == 0) { F = imgF; boxes = img_boxes; outp = img_out; W = IMG_W; H = IMG_H; }
    else            { F = bevF; boxes = bev_boxes; outp = bev_out; W = BEV_W; H = BEV_H; }

    int lane = threadIdx.x;
    float bx1 = boxes[b*4+0], by1 = boxes[b*4+1];
    float bx2 = boxes[b*4+2], by2 = boxes[b*4+3];

    __shared__ int   s_row0[S_GRID], s_row1[S_GRID];  // y0*W, y1*W (element offsets)
    __shared__ float s_wy[S_GRID];

    int x0i = 0, x1i = 0;
    float wx = 0.0f;
    if (lane < S_GRID) {
        float g = ((float)lane + 0.5f) / (float)S_GRID;
        float c1 = bx1 - 0.5f, c2 = bx2 - 0.5f;
        float xs = c1 + g * (c2 - c1);
        float x0f = fminf(fmaxf(floorf(xs), 0.0f), (float)(W-1));
        wx = fminf(fmaxf(xs - x0f, 0.0f), 1.0f);
        x0i = (int)x0f;
        x1i = min(x0i + 1, W - 1);

        float d1 = by1 - 0.5f, d2 = by2 - 0.5f;
        float ys = d1 + g * (d2 - d1);
        float y0f = fminf(fmaxf(floorf(ys), 0.0f), (float)(H-1));
        float wyv = fminf(fmaxf(ys - y0f, 0.0f), 1.0f);
        int y0 = (int)y0f;
        int y1 = min(y0 + 1, H - 1);
        s_row0[lane] = y0 * W;
        s_row1[lane] = y1 * W;
        s_wy[lane] = wyv;
    }
    __syncthreads();

    const float* f = F;   // advance by W*H per channel
    float* op = outp + (size_t)b * D_FEAT;
    for (int c = 0; c < C_FEAT; c++) {
        #pragma unroll
        for (int py = 0; py < ROI; py++) {
            float pl = 0.0f;     // per-lane accumulation over the 6 sub-rows
            #pragma unroll
            for (int sy = 0; sy < SR; sy++) {
                int yi = py * SR + sy;
                int r0 = s_row0[yi], r1 = s_row1[yi];   // LDS broadcast
                float wy = s_wy[yi];
                if (lane < S_GRID) {
                    float v00 = f[r0 + x0i], v01 = f[r0 + x1i];
                    float v10 = f[r1 + x0i], v11 = f[r1 + x1i];
                    float top = fmaf(wx, v01 - v00, v00);
                    float bot = fmaf(wx, v11 - v10, v10);
                    pl += fmaf(wy, bot - top, top);
                }
            }
            // segmented sum over groups of 6 lanes; valid at lanes 0,6,...,36
            float s = pl;
            #pragma unroll
            for (int k = 1; k < 6; k++) s += __shfl_down(pl, k);
            if (lane < S_GRID && (lane % 6) == 0)
                op[c * 49 + py * ROI + lane / 6] = s;
        }
        f += W * H;
    }
}

// ---------------- K3: GEMM1, 64x128 tile, 4x8/thread, fused A combine -------
// A = (w0*img_s + w1*bev_s), C = relu(A@B + bias)
__global__ __launch_bounds__(256) void gemm1_fused_kernel(
        const float* __restrict__ imgS, const float* __restrict__ bevS,
        const float* __restrict__ img_mask, const float* __restrict__ bev_mask,
        const float* __restrict__ B, const float* __restrict__ bias,
        float* __restrict__ C, int M, int N, int K) {
    __shared__ float As[8][64];
    __shared__ float Bs[8][128];
    float m0m = img_mask[0], m1m = bev_mask[0];
    float inv = 1.0f / ((m0m + m1m) * 36.0f);
    float w0 = m0m * inv, w1 = m1m * inv;
    int tid = threadIdx.x;
    int tx = tid & 15, ty = tid >> 4;         // cols tx*8, rows ty*4
    int m0 = blockIdx.y * 64, n0 = blockIdx.x * 128;
    float acc[4][8] = {};
    int a_row = tid >> 1;                      // 0..127 (only <64 used)
    int a_k4  = (tid & 1) * 4;
    int b_row = tid >> 5;                      // 0..7
    int b_col = (tid & 31) * 4;

    const float* ApI = imgS + (size_t)(m0 + a_row) * K + a_k4;
    const float* ApB = bevS + (size_t)(m0 + a_row) * K + a_k4;
    const float* Bp  = B + (size_t)b_row * N + n0 + b_col;

    for (int k0 = 0; k0 < K; k0 += 8) {
        float4 av;
        if (tid < 128) {
            float4 ia = *(const float4*)(ApI + k0);
            float4 ba = *(const float4*)(ApB + k0);
            av.x = w0 * ia.x + w1 * ba.x;
            av.y = w0 * ia.y + w1 * ba.y;
            av.z = w0 * ia.z + w1 * ba.z;
            av.w = w0 * ia.w + w1 * ba.w;
        }
        float4 bv = *(const float4*)(Bp + (size_t)k0 * N);
        __syncthreads();
        if (tid < 128) {
            As[a_k4+0][a_row] = av.x;
            As[a_k4+1][a_row] = av.y;
            As[a_k4+2][a_row] = av.z;
            As[a_k4+3][a_row] = av.w;
        }
        *(float4*)&Bs[b_row][b_col] = bv;
        __syncthreads();
        #pragma unroll
        for (int kk = 0; kk < 8; kk++) {
            float4 a = *(const float4*)&As[kk][ty * 4];
            float4 b0 = *(const float4*)&Bs[kk][tx * 8];
            float4 b1 = *(const float4*)&Bs[kk][tx * 8 + 4];
            float aa[4] = {a.x, a.y, a.z, a.w};
            float bb[8] = {b0.x, b0.y, b0.z, b0.w, b1.x, b1.y, b1.z, b1.w};
            #pragma unroll
            for (int i = 0; i < 4; i++)
                #pragma unroll
                for (int j = 0; j < 8; j++)
                    acc[i][j] += aa[i] * bb[j];
        }
    }
    float4 bv0 = *(const float4*)(bias + n0 + tx * 8);
    float4 bv1 = *(const float4*)(bias + n0 + tx * 8 + 4);
    float bb[8] = {bv0.x, bv0.y, bv0.z, bv0.w, bv1.x, bv1.y, bv1.z, bv1.w};
    #pragma unroll
    for (int i = 0; i < 4; i++) {
        int m = m0 + ty * 4 + i;
        float4 o0, o1;
        o0.x = fmaxf(acc[i][0] + bb[0], 0.0f);
        o0.y = fmaxf(acc[i][1] + bb[1], 0.0f);
        o0.z = fmaxf(acc[i][2] + bb[2], 0.0f);
        o0.w = fmaxf(acc[i][3] + bb[3], 0.0f);
        o1.x = fmaxf(acc[i][4] + bb[4], 0.0f);
        o1.y = fmaxf(acc[i][5] + bb[5], 0.0f);
        o1.z = fmaxf(acc[i][6] + bb[6], 0.0f);
        o1.w = fmaxf(acc[i][7] + bb[7], 0.0f);
        *(float4*)(C + (size_t)m * N + n0 + tx * 8) = o0;
        *(float4*)(C + (size_t)m * N + n0 + tx * 8 + 4) = o1;
    }
}

// ---------------- K4: GEMM2 split-K=2, 128x128 tile, 8x8/thread ----------------
__global__ __launch_bounds__(256) void gemm2_splitk_kernel(
        const float* __restrict__ A, const float* __restrict__ B,
        float* __restrict__ P, int M, int N, int K) {
    int ks = blockIdx.z;
    int Kh = K >> 1;
    int kbeg = ks * Kh;
    __shared__ float As[8][128];
    __shared__ float Bs[8][128];
    int tid = threadIdx.x;
    int tx = tid & 15, ty = tid >> 4;         // cols tx*8, rows ty*8
    int m0 = blockIdx.y * 128, n0 = blockIdx.x * 128;
    float acc[8][8] = {};
    int a_row = tid >> 1;                      // 0..127
    int a_k4  = (tid & 1) * 4;
    int b_row = tid >> 5;                      // 0..7
    int b_col = (tid & 31) * 4;

    const float* Ap = A + (size_t)(m0 + a_row) * K + kbeg + a_k4;
    const float* Bp = B + (size_t)(kbeg + b_row) * N + n0 + b_col;

    for (int k0 = 0; k0 < Kh; k0 += 8) {
        float4 av = *(const float4*)(Ap + k0);
        float4 bv = *(const float4*)(Bp + (size_t)k0 * N);
        __syncthreads();
        As[a_k4+0][a_row] = av.x;
        As[a_k4+1][a_row] = av.y;
        As[a_k4+2][a_row] = av.z;
        As[a_k4+3][a_row] = av.w;
        *(float4*)&Bs[b_row][b_col] = bv;
        __syncthreads();
        #pragma unroll
        for (int kk = 0; kk < 8; kk++) {
            float4 a0 = *(const float4*)&As[kk][ty * 8];
            float4 a1 = *(const float4*)&As[kk][ty * 8 + 4];
            float4 b0 = *(const float4*)&Bs[kk][tx * 8];
            float4 b1 = *(const float4*)&Bs[kk][tx * 8 + 4];
            float aa[8] = {a0.x, a0.y, a0.z, a0.w, a1.x, a1.y, a1.z, a1.w};
            float bb[8] = {b0.x, b0.y, b0.z, b0.w, b1.x, b1.y, b1.z, b1.w};
            #pragma unroll
            for (int i = 0; i < 8; i++)
                #pragma unroll
                for (int j = 0; j < 8; j++)
                    acc[i][j] += aa[i] * bb[j];
        }
    }
    float* Pp = P + (size_t)ks * M * N;
    #pragma unroll
    for (int i = 0; i < 8; i++) {
        int m = m0 + ty * 8 + i;
        *(float4*)(Pp + (size_t)m * N + n0 + tx * 8)     = *(float4*)&acc[i][0];
        *(float4*)(Pp + (size_t)m * N + n0 + tx * 8 + 4) = *(float4*)&acc[i][4];
    }
}

// ---------------- K5: combine split-K partials + bias + relu ----------------
__global__ __launch_bounds__(256) void combine_relu_kernel(
        const float* __restrict__ P, const float* __restrict__ bias,
        float* __restrict__ C, int total, int N) {
    int i4 = blockIdx.x * blockDim.x + threadIdx.x;
    int flat = i4 * 4;
    if (flat >= total) return;
    int n = flat % N;
    float4 p0 = *(const float4*)(P + flat);
    float4 p1 = *(const float4*)(P + (size_t)total + flat);
    float4 bb = *(const float4*)(bias + n);
    float4 o;
    o.x = fmaxf(p0.x + p1.x + bb.x, 0.0f);
    o.y = fmaxf(p0.y + p1.y + bb.y, 0.0f);
    o.z = fmaxf(p0.z + p1.z + bb.z, 0.0f);
    o.w = fmaxf(p0.w + p1.w + bb.w, 0.0f);
    *(float4*)(C + flat) = o;
}

// ---------------- K6: heads (obj/off/ang) + postprocess per row ----------------
__global__ __launch_bounds__(256) void heads_kernel(
        const float* __restrict__ h,
        const float* __restrict__ Wc, const float* __restrict__ bc,
        const float* __restrict__ Wo, const float* __restrict__ bo,
        const float* __restrict__ Wa, const float* __restrict__ ba,
        const float* __restrict__ anchors,
        float* __restrict__ obj_soft, float* __restrict__ off_out,
        float* __restrict__ orient, float* __restrict__ pred,
        float* __restrict__ pbev, float* __restrict__ scores) {
    int row = blockIdx.x;
    const float* hr = h + (size_t)row * HID;
    float acc[14];
    #pragma unroll
    for (int j = 0; j < 14; j++) acc[j] = 0.0f;
    for (int k = threadIdx.x; k < HID; k += 256) {
        float hv = hr[k];
        acc[0]  += hv * Wc[k*2+0];
        acc[1]  += hv * Wc[k*2+1];
        #pragma unroll
        for (int j = 0; j < 10; j++) acc[2+j] += hv * Wo[k*10+j];
        acc[12] += hv * Wa[k*2+0];
        acc[13] += hv * Wa[k*2+1];
    }
    #pragma unroll
    for (int d = 32; d > 0; d >>= 1) {
        #pragma unroll
        for (int j = 0; j < 14; j++) acc[j] += __shfl_down(acc[j], d);
    }
    __shared__ float red[4][14];
    int wid = threadIdx.x >> 6, lane = threadIdx.x & 63;
    if (lane == 0) {
        #pragma unroll
        for (int j = 0; j < 14; j++) red[wid][j] = acc[j];
    }
    __syncthreads();
    if (threadIdx.x == 0) {
        float f[14];
        #pragma unroll
        for (int j = 0; j < 14; j++)
            f[j] = red[0][j] + red[1][j] + red[2][j] + red[3][j];
        float obj0 = f[0] + bc[0], obj1 = f[1] + bc[1];
        float offv[10];
        #pragma unroll
        for (int j = 0; j < 10; j++) offv[j] = f[2+j] + bo[j];
        float ang0 = f[12] + ba[0], ang1 = f[13] + ba[1];
        float mx = fmaxf(obj0, obj1);
        float e0 = expf(obj0 - mx), e1 = expf(obj1 - mx);
        float den = e0 + e1;
        obj_soft[row*2+0] = e0 / den;
        obj_soft[row*2+1] = e1 / den;
        scores[row] = obj1;
        orient[row] = atan2f(ang1, ang0);
        float pa[6];
        #pragma unroll
        for (int j = 0; j < 6; j++) {
            pa[j] = anchors[row*6+j] + offv[j];
            pred[row*6+j] = pa[j];
        }
        #pragma unroll
        for (int j = 0; j < 10; j++) off_out[row*10+j] = offv[j];
        float x = pa[0], z = pa[2], ddx = pa[3], ddz = pa[5];
        pbev[row*4+0] = ((x - ddx*0.5f) - (-40.0f)) / 0.1f;
        pbev[row*4+1] = (70.0f - (z + ddz*0.5f)) / 0.1f;
        pbev[row*4+2] = ((x + ddx*0.5f) - (-40.0f)) / 0.1f;
        pbev[row*4+3] = (70.0f - (z - ddz*0.5f)) / 0.1f;
    }
}

// ---------------- K7: sequential NMS, single wave, fused suppress+argmax -------
__global__ void nms_kernel(const float* __restrict__ boxes,
                           const float* __restrict__ scores_g,
                           int* __restrict__ idx_out) {
    __shared__ float4 sb4[N_PROP];
    __shared__ float  sa[N_PROP];
    int lane = threadIdx.x;   // 64 threads
    float sc[16], x1v[16], y1v[16], x2v[16], y2v[16], ar[16];
    const float4* bp = (const float4*)boxes;
    #pragma unroll
    for (int j = 0; j < 16; j++) {
        int g = lane + 64*j;
        float4 bb = bp[g];
        x1v[j] = bb.x; y1v[j] = bb.y; x2v[j] = bb.z; y2v[j] = bb.w;
        ar[j] = (bb.z - bb.x) * (bb.w - bb.y);
        sc[j] = scores_g[g];
        sb4[g] = bb;
        sa[g] = ar[j];
    }
    // initial per-lane argmax (first-index tie-break: ascending g, strict >)
    float bv = sc[0]; int bi = lane;
    #pragma unroll
    for (int j = 1; j < 16; j++) {
        int g = lane + 64*j;
        if (sc[j] > bv) { bv = sc[j]; bi = g; }
    }
    for (int t = 0; t < NMS_K; t++) {
        // cross-lane butterfly argmax, min-index on ties
        #pragma unroll
        for (int d = 1; d < 64; d <<= 1) {
            float ov = __shfl_xor(bv, d);
            int   oi = __shfl_xor(bi, d);
            if (ov > bv || (ov == bv && oi < bi)) { bv = ov; bi = oi; }
        }
        if (lane == 0) idx_out[t] = bi;
        float4 pb = sb4[bi];
        float pa = sa[bi];
        // fused suppress + next argmax
        float nbv; int nbi;
        {
            int g = lane;
            float xx1 = fmaxf(x1v[0], pb.x), yy1 = fmaxf(y1v[0], pb.y);
            float xx2 = fminf(x2v[0], pb.z), yy2 = fminf(y2v[0], pb.w);
            float inter = fmaxf(xx2 - xx1, 0.0f) * fmaxf(yy2 - yy1, 0.0f);
            float iou = inter / (ar[0] + pa - inter + 1e-6f);
            if (iou > NMS_THR || g == bi) sc[0] = -INFINITY;
            nbv = sc[0]; nbi = g;
        }
        #pragma unroll
        for (int j = 1; j < 16; j++) {
            int g = lane + 64*j;
            float xx1 = fmaxf(x1v[j], pb.x), yy1 = fmaxf(y1v[j], pb.y);
            float xx2 = fminf(x2v[j], pb.z), yy2 = fminf(y2v[j], pb.w);
            float inter = fmaxf(xx2 - xx1, 0.0f) * fmaxf(yy2 - yy1, 0.0f);
            float iou = inter / (ar[j] + pa - inter + 1e-6f);
            if (iou > NMS_THR || g == bi) sc[j] = -INFINITY;
            if (sc[j] > nbv) { nbv = sc[j]; nbi = g; }
        }
        bv = nbv; bi = nbi;
    }
}

// ---------------- K8: gather outputs ----------------
__global__ void gather_kernel(const int* __restrict__ idx,
                              const float* __restrict__ obj_soft,
                              const float* __restrict__ pred,
                              const float* __restrict__ off,
                              const float* __restrict__ orient,
                              float* __restrict__ out) {
    int i = threadIdx.x;
    if (i < NMS_K) {
        int j = idx[i];
        out[2*i+0] = obj_soft[j*2+0];
        out[2*i+1] = obj_soft[j*2+1];
        #pragma unroll
        for (int t = 0; t < 6; t++) out[200 + 6*i + t] = pred[j*6+t];
        #pragma unroll
        for (int t = 0; t < 10; t++) out[800 + 10*i + t] = off[j*10+t];
        #pragma unroll
        for (int t = 0; t < 6; t++) out[1800 + 7*i + t] = pred[j*6+t];
        out[1800 + 7*i + 6] = 0.0f;
        out[2500 + i] = orient[j];
    }
}

extern "C" void kernel_launch(void* const* d_in, const int* in_sizes, int n_in,
                              void* d_out, int out_size, void* d_ws, size_t ws_size,
                              hipStream_t stream) {
    const float* imgF     = (const float*)d_in[0];
    const float* bevF     = (const float*)d_in[1];
    const float* anchors  = (const float*)d_in[2];
    const float* calib    = (const float*)d_in[3];
    const float* img_mask = (const float*)d_in[5];
    const float* bev_mask = (const float*)d_in[6];
    const float* W1 = (const float*)d_in[7];
    const float* b1 = (const float*)d_in[8];
    const float* W2 = (const float*)d_in[9];
    const float* b2 = (const float*)d_in[10];
    const float* Wc = (const float*)d_in[11];
    const float* bc = (const float*)d_in[12];
    const float* Wo = (const float*)d_in[13];
    const float* bo = (const float*)d_in[14];
    const float* Wa = (const float*)d_in[15];
    const float* ba = (const float*)d_in[16];
    const int* image_shape = (const int*)d_in[17];

    float* ws = (float*)d_ws;
    float* img_boxes = ws + WS_IMG_BOXES;
    float* bev_boxes = ws + WS_BEV_BOXES;
    float* obj_soft  = ws + WS_OBJS;
    float* off       = ws + WS_OFF;
    float* orient    = ws + WS_ORIENT;
    float* pred      = ws + WS_PRED;
    float* pbev      = ws + WS_PBEV;
    float* scores    = ws + WS_SCORES;
    int*   idx       = (int*)(ws + WS_IDX);
    float* img_s     = ws + WS_A;            // 1024*1568 in region A
    float* bev_s     = ws + WS_B;            // 1024*1568 in region B
    float* h1        = ws + WS_C;            // 1024*2048
    float* P2        = ws + WS_A;            // split-K partials (A+B, 2x 2M)
    float* h2        = ws + WS_C;            // overwrites h1 after GEMM2

    boxes_kernel<<<N_PROP/64, 64, 0, stream>>>(anchors, calib, image_shape,
                                               img_boxes, bev_boxes);
    roi_map_kernel<<<dim3(N_PROP, 2), 64, 0, stream>>>(
        imgF, bevF, img_boxes, bev_boxes, img_s, bev_s);
    gemm1_fused_kernel<<<dim3(HID/128, N_PROP/64), 256, 0, stream>>>(
        img_s, bev_s, img_mask, bev_mask, W1, b1, h1, N_PROP, HID, D_FEAT);
    gemm2_splitk_kernel<<<dim3(HID/128, N_PROP/128, 2), 256, 0, stream>>>(
        h1, W2, P2, N_PROP, HID, HID);
    combine_relu_kernel<<<(N_PROP*HID/4 + 255)/256, 256, 0, stream>>>(
        P2, b2, h2, N_PROP*HID, HID);
    heads_kernel<<<N_PROP, 256, 0, stream>>>(h2, Wc, bc, Wo, bo, Wa, ba, anchors,
                                             obj_soft, off, orient, pred, pbev, scores);
    nms_kernel<<<1, 64, 0, stream>>>(pbev, scores, idx);
    gather_kernel<<<1, 128, 0, stream>>>(idx, obj_soft, pred, off, orient,
                                         (float*)d_out);
}

// Round 4
// 1533.052 us; speedup vs baseline: 1.1840x; 1.1840x over previous
//
#include <hip/hip_runtime.h>
#include <math.h>

#define N_PROP 1024
#define C_FEAT 32
#define ROI 7
#define SR 6
#define S_GRID 42
#define IMG_H 360
#define IMG_W 1200
#define BEV_H 700
#define BEV_W 800
#define D_FEAT (C_FEAT*ROI*ROI)   // 1568
#define HID 2048
#define NMS_K 100
#define NMS_THR 0.01f

// ---------------- workspace layout (float offsets) ----------------
// Regions A/B/C are 2M floats each. Lifetimes:
//   roi:    img_s -> A, bev_s -> B
//   gemm1:  reads A,B -> writes h1 -> C
//   gemm2:  reads C   -> writes h2 -> A (img_s dead)
#define WS_IMG_BOXES 0
#define WS_BEV_BOXES (WS_IMG_BOXES + 4*N_PROP)
#define WS_OBJS      (WS_BEV_BOXES + 4*N_PROP)
#define WS_OFF       (WS_OBJS + 2*N_PROP)
#define WS_ORIENT    (WS_OFF + 10*N_PROP)
#define WS_PRED      (WS_ORIENT + N_PROP)
#define WS_PBEV      (WS_PRED + 6*N_PROP)
#define WS_SCORES    (WS_PBEV + 4*N_PROP)
#define WS_IDX       (WS_SCORES + N_PROP)   // ints (100)
#define WS_A         40960
#define WS_B         (WS_A + N_PROP*HID)
#define WS_C         (WS_B + N_PROP*HID)

// ---------------- K1: project boxes ----------------
__global__ void boxes_kernel(const float* __restrict__ anchors,
                             const float* __restrict__ calib,
                             const int* __restrict__ imshape,
                             float* __restrict__ img_boxes,
                             float* __restrict__ bev_boxes) {
    int n = blockIdx.x * blockDim.x + threadIdx.x;
    if (n >= N_PROP) return;
    float x = anchors[n*6+0], y = anchors[n*6+1], z = anchors[n*6+2];
    float dx = anchors[n*6+3], dy = anchors[n*6+4], dz = anchors[n*6+5];

    bev_boxes[n*4+0] = ((x - dx*0.5f) - (-40.0f)) / 0.1f;
    bev_boxes[n*4+1] = (70.0f - (z + dz*0.5f)) / 0.1f;
    bev_boxes[n*4+2] = ((x + dx*0.5f) - (-40.0f)) / 0.1f;
    bev_boxes[n*4+3] = (70.0f - (z - dz*0.5f)) / 0.1f;

    float P[12];
    #pragma unroll
    for (int i = 0; i < 12; i++) P[i] = calib[i];

    float umin = 1e30f, vmin = 1e30f, umax = -1e30f, vmax = -1e30f;
    #pragma unroll
    for (int k = 0; k < 8; k++) {
        float fsx = (k & 4) ? 1.0f : -1.0f;
        float fsy = (k & 2) ? 1.0f : -1.0f;
        float fsz = (k & 1) ? 1.0f : -1.0f;
        float cx = x + fsx * dx * 0.5f;
        float cy = y + fsy * dy * 0.5f;
        float cz = z + fsz * dz * 0.5f;
        float p0 = P[0]*cx + P[1]*cy + P[2]*cz + P[3];
        float p1 = P[4]*cx + P[5]*cy + P[6]*cz + P[7];
        float p2 = P[8]*cx + P[9]*cy + P[10]*cz + P[11];
        float zz = fmaxf(p2, 0.1f);
        float u = p0 / zz, v = p1 / zz;
        umin = fminf(umin, u); umax = fmaxf(umax, u);
        vmin = fminf(vmin, v); vmax = fmaxf(vmax, v);
    }
    float Hf = (float)imshape[0];
    float Wf = (float)imshape[1];
    img_boxes[n*4+0] = fminf(fmaxf(umin, 0.0f), Wf);
    img_boxes[n*4+1] = fminf(fmaxf(vmin, 0.0f), Hf);
    img_boxes[n*4+2] = fminf(fmaxf(umax, 0.0f), Wf);
    img_boxes[n*4+3] = fminf(fmaxf(vmax, 0.0f), Hf);
}

// ---------------- K2: roi_align ----------------
// Grid (4 channel-groups, 1024 boxes, 2 maps) = 8192 single-wave blocks
// (32 waves/CU for latency hiding). Each wave: geometry once, then 8 channels
// with `#pragma unroll 1` (keeps VGPR low; R2's unrolled c-loop hit 252 VGPR
// and 9.7% occupancy). Shuffle-6 reduce once per output row.
__global__ __launch_bounds__(64) void roi_map_kernel(
        const float* __restrict__ imgF, const float* __restrict__ bevF,
        const float* __restrict__ img_boxes, const float* __restrict__ bev_boxes,
        float* __restrict__ img_out, float* __restrict__ bev_out) {
    int cg = blockIdx.x;     // channel group 0..3 (8 channels each)
    int b  = blockIdx.y;     // box 0..1023
    int mapid = blockIdx.z;  // 0=img, 1=bev

    const float* F; const float* boxes; float* outp; int W, H;
    if (mapid == 0) { F = imgF; boxes = img_boxes; outp = img_out; W = IMG_W; H = IMG_H; }
    else            { F = bevF; boxes = bev_boxes; outp = bev_out; W = BEV_W; H = BEV_H; }

    int lane = threadIdx.x;
    float bx1 = boxes[b*4+0], by1 = boxes[b*4+1];
    float bx2 = boxes[b*4+2], by2 = boxes[b*4+3];

    __shared__ int   s_row0[S_GRID], s_row1[S_GRID];  // y0*W, y1*W element offsets
    __shared__ float s_wy[S_GRID];

    int x0i = 0, x1i = 0;
    float wx = 0.0f;
    if (lane < S_GRID) {
        float g = ((float)lane + 0.5f) / (float)S_GRID;
        float c1 = bx1 - 0.5f, c2 = bx2 - 0.5f;
        float xs = c1 + g * (c2 - c1);
        float x0f = fminf(fmaxf(floorf(xs), 0.0f), (float)(W-1));
        wx = fminf(fmaxf(xs - x0f, 0.0f), 1.0f);
        x0i = (int)x0f;
        x1i = min(x0i + 1, W - 1);

        float d1 = by1 - 0.5f, d2 = by2 - 0.5f;
        float ys = d1 + g * (d2 - d1);
        float y0f = fminf(fmaxf(floorf(ys), 0.0f), (float)(H-1));
        float wyv = fminf(fmaxf(ys - y0f, 0.0f), 1.0f);
        int y0 = (int)y0f;
        int y1 = min(y0 + 1, H - 1);
        s_row0[lane] = y0 * W;
        s_row1[lane] = y1 * W;
        s_wy[lane] = wyv;
    }
    __syncthreads();

    const float* f = F + (size_t)(cg * 8) * W * H;
    float* op = outp + (size_t)b * D_FEAT + (cg * 8) * 49;
    #pragma unroll 1
    for (int cc = 0; cc < 8; cc++) {
        #pragma unroll
        for (int py = 0; py < ROI; py++) {
            float pl = 0.0f;     // per-lane accumulation over the 6 sub-rows
            #pragma unroll
            for (int sy = 0; sy < SR; sy++) {
                int yi = py * SR + sy;
                int r0 = s_row0[yi], r1 = s_row1[yi];   // LDS broadcast
                float wy = s_wy[yi];
                if (lane < S_GRID) {
                    float v00 = f[r0 + x0i], v01 = f[r0 + x1i];
                    float v10 = f[r1 + x0i], v11 = f[r1 + x1i];
                    float top = fmaf(wx, v01 - v00, v00);
                    float bot = fmaf(wx, v11 - v10, v10);
                    pl += fmaf(wy, bot - top, top);
                }
            }
            // segmented sum over groups of 6 lanes; valid at lanes 0,6,...,36
            float s = pl;
            #pragma unroll
            for (int k = 1; k < 6; k++) s += __shfl_down(pl, k);
            if (lane < S_GRID && (lane % 6) == 0)
                op[py * ROI + lane / 6] = s;
        }
        f += W * H;
        op += 49;
    }
}

// ---------------- K3: GEMM1 (R1-proven 64x64) with fused A combine ----------
#define GBM 64
#define GBN 64
#define GBK 16
__global__ __launch_bounds__(256) void gemm_fusedA_relu_kernel(
        const float* __restrict__ imgS, const float* __restrict__ bevS,
        const float* __restrict__ img_mask, const float* __restrict__ bev_mask,
        const float* __restrict__ B, const float* __restrict__ bias,
        float* __restrict__ C, int M, int N, int K) {
    __shared__ float As[GBK][GBM + 4];
    __shared__ float Bs[GBK][GBN];
    float m0 = img_mask[0], m1 = bev_mask[0];
    float inv = 1.0f / ((m0 + m1) * 36.0f);
    float w0 = m0 * inv, w1 = m1 * inv;
    int tid = threadIdx.x;
    int tx = tid & 15, ty = tid >> 4;
    int m0i = blockIdx.y * GBM, n0 = blockIdx.x * GBN;
    float acc[4][4] = {};
    int arow = tid >> 2;
    int acg  = (tid & 3) << 2;
    int brow = tid >> 4;
    int bcol = (tid & 15) << 2;

    for (int k0 = 0; k0 < K; k0 += GBK) {
        size_t aidx = (size_t)(m0i + arow) * K + k0 + acg;
        float4 ia = *(const float4*)(imgS + aidx);
        float4 ba = *(const float4*)(bevS + aidx);
        float4 av;
        av.x = w0 * ia.x + w1 * ba.x;
        av.y = w0 * ia.y + w1 * ba.y;
        av.z = w0 * ia.z + w1 * ba.z;
        av.w = w0 * ia.w + w1 * ba.w;
        float4 bv = *(const float4*)(B + (size_t)(k0 + brow) * N + n0 + bcol);
        __syncthreads();
        As[acg+0][arow] = av.x;
        As[acg+1][arow] = av.y;
        As[acg+2][arow] = av.z;
        As[acg+3][arow] = av.w;
        *(float4*)&Bs[brow][bcol] = bv;
        __syncthreads();
        #pragma unroll
        for (int kk = 0; kk < GBK; kk++) {
            float4 a = *(const float4*)&As[kk][ty * 4];
            float4 b = *(const float4*)&Bs[kk][tx * 4];
            float aa[4] = {a.x, a.y, a.z, a.w};
            float bb[4] = {b.x, b.y, b.z, b.w};
            #pragma unroll
            for (int i = 0; i < 4; i++)
                #pragma unroll
                for (int j = 0; j < 4; j++)
                    acc[i][j] += aa[i] * bb[j];
        }
    }
    float4 bv = *(const float4*)(bias + n0 + tx * 4);
    float bb[4] = {bv.x, bv.y, bv.z, bv.w};
    #pragma unroll
    for (int i = 0; i < 4; i++) {
        int m = m0i + ty * 4 + i;
        float4 o;
        o.x = fmaxf(acc[i][0] + bb[0], 0.0f);
        o.y = fmaxf(acc[i][1] + bb[1], 0.0f);
        o.z = fmaxf(acc[i][2] + bb[2], 0.0f);
        o.w = fmaxf(acc[i][3] + bb[3], 0.0f);
        *(float4*)(C + (size_t)m * N + n0 + tx * 4) = o;
    }
}

// ---------------- K4: plain fp32 tiled GEMM (R1-proven), relu ----------------
__global__ __launch_bounds__(256) void gemm_relu_kernel(
        const float* __restrict__ A, const float* __restrict__ B,
        const float* __restrict__ bias, float* __restrict__ C,
        int M, int N, int K, int do_relu) {
    __shared__ float As[GBK][GBM + 4];
    __shared__ float Bs[GBK][GBN];
    int tid = threadIdx.x;
    int tx = tid & 15, ty = tid >> 4;
    int m0 = blockIdx.y * GBM, n0 = blockIdx.x * GBN;
    float acc[4][4] = {};
    int arow = tid >> 2;
    int acg  = (tid & 3) << 2;
    int brow = tid >> 4;
    int bcol = (tid & 15) << 2;

    for (int k0 = 0; k0 < K; k0 += GBK) {
        float4 av = *(const float4*)(A + (size_t)(m0 + arow) * K + k0 + acg);
        float4 bv = *(const float4*)(B + (size_t)(k0 + brow) * N + n0 + bcol);
        __syncthreads();
        As[acg+0][arow] = av.x;
        As[acg+1][arow] = av.y;
        As[acg+2][arow] = av.z;
        As[acg+3][arow] = av.w;
        *(float4*)&Bs[brow][bcol] = bv;
        __syncthreads();
        #pragma unroll
        for (int kk = 0; kk < GBK; kk++) {
            float4 a = *(const float4*)&As[kk][ty * 4];
            float4 b = *(const float4*)&Bs[kk][tx * 4];
            float aa[4] = {a.x, a.y, a.z, a.w};
            float bb[4] = {b.x, b.y, b.z, b.w};
            #pragma unroll
            for (int i = 0; i < 4; i++)
                #pragma unroll
                for (int j = 0; j < 4; j++)
                    acc[i][j] += aa[i] * bb[j];
        }
    }
    float4 bv = *(const float4*)(bias + n0 + tx * 4);
    float bb[4] = {bv.x, bv.y, bv.z, bv.w};
    #pragma unroll
    for (int i = 0; i < 4; i++) {
        int m = m0 + ty * 4 + i;
        float4 o;
        float v0 = acc[i][0] + bb[0];
        float v1 = acc[i][1] + bb[1];
        float v2 = acc[i][2] + bb[2];
        float v3 = acc[i][3] + bb[3];
        if (do_relu) {
            v0 = fmaxf(v0, 0.0f); v1 = fmaxf(v1, 0.0f);
            v2 = fmaxf(v2, 0.0f); v3 = fmaxf(v3, 0.0f);
        }
        o.x = v0; o.y = v1; o.z = v2; o.w = v3;
        *(float4*)(C + (size_t)m * N + n0 + tx * 4) = o;
    }
}

// ---------------- K5: heads (obj/off/ang) + postprocess per row ----------------
__global__ __launch_bounds__(256) void heads_kernel(
        const float* __restrict__ h,
        const float* __restrict__ Wc, const float* __restrict__ bc,
        const float* __restrict__ Wo, const float* __restrict__ bo,
        const float* __restrict__ Wa, const float* __restrict__ ba,
        const float* __restrict__ anchors,
        float* __restrict__ obj_soft, float* __restrict__ off_out,
        float* __restrict__ orient, float* __restrict__ pred,
        float* __restrict__ pbev, float* __restrict__ scores) {
    int row = blockIdx.x;
    const float* hr = h + (size_t)row * HID;
    float acc[14];
    #pragma unroll
    for (int j = 0; j < 14; j++) acc[j] = 0.0f;
    for (int k = threadIdx.x; k < HID; k += 256) {
        float hv = hr[k];
        acc[0]  += hv * Wc[k*2+0];
        acc[1]  += hv * Wc[k*2+1];
        #pragma unroll
        for (int j = 0; j < 10; j++) acc[2+j] += hv * Wo[k*10+j];
        acc[12] += hv * Wa[k*2+0];
        acc[13] += hv * Wa[k*2+1];
    }
    #pragma unroll
    for (int d = 32; d > 0; d >>= 1) {
        #pragma unroll
        for (int j = 0; j < 14; j++) acc[j] += __shfl_down(acc[j], d);
    }
    __shared__ float red[4][14];
    int wid = threadIdx.x >> 6, lane = threadIdx.x & 63;
    if (lane == 0) {
        #pragma unroll
        for (int j = 0; j < 14; j++) red[wid][j] = acc[j];
    }
    __syncthreads();
    if (threadIdx.x == 0) {
        float f[14];
        #pragma unroll
        for (int j = 0; j < 14; j++)
            f[j] = red[0][j] + red[1][j] + red[2][j] + red[3][j];
        float obj0 = f[0] + bc[0], obj1 = f[1] + bc[1];
        float offv[10];
        #pragma unroll
        for (int j = 0; j < 10; j++) offv[j] = f[2+j] + bo[j];
        float ang0 = f[12] + ba[0], ang1 = f[13] + ba[1];
        float mx = fmaxf(obj0, obj1);
        float e0 = expf(obj0 - mx), e1 = expf(obj1 - mx);
        float den = e0 + e1;
        obj_soft[row*2+0] = e0 / den;
        obj_soft[row*2+1] = e1 / den;
        scores[row] = obj1;
        orient[row] = atan2f(ang1, ang0);
        float pa[6];
        #pragma unroll
        for (int j = 0; j < 6; j++) {
            pa[j] = anchors[row*6+j] + offv[j];
            pred[row*6+j] = pa[j];
        }
        #pragma unroll
        for (int j = 0; j < 10; j++) off_out[row*10+j] = offv[j];
        float x = pa[0], z = pa[2], ddx = pa[3], ddz = pa[5];
        pbev[row*4+0] = ((x - ddx*0.5f) - (-40.0f)) / 0.1f;
        pbev[row*4+1] = (70.0f - (z + ddz*0.5f)) / 0.1f;
        pbev[row*4+2] = ((x + ddx*0.5f) - (-40.0f)) / 0.1f;
        pbev[row*4+3] = (70.0f - (z - ddz*0.5f)) / 0.1f;
    }
}

// ---------------- K6: sequential NMS, single wave, fused suppress+argmax -------
__global__ void nms_kernel(const float* __restrict__ boxes,
                           const float* __restrict__ scores_g,
                           int* __restrict__ idx_out) {
    __shared__ float4 sb4[N_PROP];
    __shared__ float  sa[N_PROP];
    int lane = threadIdx.x;   // 64 threads
    float sc[16], x1v[16], y1v[16], x2v[16], y2v[16], ar[16];
    const float4* bp = (const float4*)boxes;
    #pragma unroll
    for (int j = 0; j < 16; j++) {
        int g = lane + 64*j;
        float4 bb = bp[g];
        x1v[j] = bb.x; y1v[j] = bb.y; x2v[j] = bb.z; y2v[j] = bb.w;
        ar[j] = (bb.z - bb.x) * (bb.w - bb.y);
        sc[j] = scores_g[g];
        sb4[g] = bb;
        sa[g] = ar[j];
    }
    // initial per-lane argmax (first-index tie-break: ascending g, strict >)
    float bv = sc[0]; int bi = lane;
    #pragma unroll
    for (int j = 1; j < 16; j++) {
        int g = lane + 64*j;
        if (sc[j] > bv) { bv = sc[j]; bi = g; }
    }
    for (int t = 0; t < NMS_K; t++) {
        #pragma unroll
        for (int d = 1; d < 64; d <<= 1) {
            float ov = __shfl_xor(bv, d);
            int   oi = __shfl_xor(bi, d);
            if (ov > bv || (ov == bv && oi < bi)) { bv = ov; bi = oi; }
        }
        if (lane == 0) idx_out[t] = bi;
        float4 pb = sb4[bi];
        float pa = sa[bi];
        float nbv = -INFINITY; int nbi = lane;
        #pragma unroll
        for (int j = 0; j < 16; j++) {
            int g = lane + 64*j;
            float xx1 = fmaxf(x1v[j], pb.x), yy1 = fmaxf(y1v[j], pb.y);
            float xx2 = fminf(x2v[j], pb.z), yy2 = fminf(y2v[j], pb.w);
            float inter = fmaxf(xx2 - xx1, 0.0f) * fmaxf(yy2 - yy1, 0.0f);
            float iou = inter / (ar[j] + pa - inter + 1e-6f);
            if (iou > NMS_THR || g == bi) sc[j] = -INFINITY;
            if (sc[j] > nbv) { nbv = sc[j]; nbi = g; }
        }
        bv = nbv; bi = nbi;
    }
}

// ---------------- K7: gather outputs ----------------
__global__ void gather_kernel(const int* __restrict__ idx,
                              const float* __restrict__ obj_soft,
                              const float* __restrict__ pred,
                              const float* __restrict__ off,
                              const float* __restrict__ orient,
                              float* __restrict__ out) {
    int i = threadIdx.x;
    if (i < NMS_K) {
        int j = idx[i];
        out[2*i+0] = obj_soft[j*2+0];
        out[2*i+1] = obj_soft[j*2+1];
        #pragma unroll
        for (int t = 0; t < 6; t++) out[200 + 6*i + t] = pred[j*6+t];
        #pragma unroll
        for (int t = 0; t < 10; t++) out[800 + 10*i + t] = off[j*10+t];
        #pragma unroll
        for (int t = 0; t < 6; t++) out[1800 + 7*i + t] = pred[j*6+t];
        out[1800 + 7*i + 6] = 0.0f;
        out[2500 + i] = orient[j];
    }
}

extern "C" void kernel_launch(void* const* d_in, const int* in_sizes, int n_in,
                              void* d_out, int out_size, void* d_ws, size_t ws_size,
                              hipStream_t stream) {
    const float* imgF     = (const float*)d_in[0];
    const float* bevF     = (const float*)d_in[1];
    const float* anchors  = (const float*)d_in[2];
    const float* calib    = (const float*)d_in[3];
    const float* img_mask = (const float*)d_in[5];
    const float* bev_mask = (const float*)d_in[6];
    const float* W1 = (const float*)d_in[7];
    const float* b1 = (const float*)d_in[8];
    const float* W2 = (const float*)d_in[9];
    const float* b2 = (const float*)d_in[10];
    const float* Wc = (const float*)d_in[11];
    const float* bc = (const float*)d_in[12];
    const float* Wo = (const float*)d_in[13];
    const float* bo = (const float*)d_in[14];
    const float* Wa = (const float*)d_in[15];
    const float* ba = (const float*)d_in[16];
    const int* image_shape = (const int*)d_in[17];

    float* ws = (float*)d_ws;
    float* img_boxes = ws + WS_IMG_BOXES;
    float* bev_boxes = ws + WS_BEV_BOXES;
    float* obj_soft  = ws + WS_OBJS;
    float* off       = ws + WS_OFF;
    float* orient    = ws + WS_ORIENT;
    float* pred      = ws + WS_PRED;
    float* pbev      = ws + WS_PBEV;
    float* scores    = ws + WS_SCORES;
    int*   idx       = (int*)(ws + WS_IDX);
    float* img_s     = ws + WS_A;            // region A
    float* bev_s     = ws + WS_B;            // region B
    float* h1        = ws + WS_C;            // region C
    float* h2        = ws + WS_A;            // reuses region A (img_s dead)

    boxes_kernel<<<N_PROP/64, 64, 0, stream>>>(anchors, calib, image_shape,
                                               img_boxes, bev_boxes);
    roi_map_kernel<<<dim3(4, N_PROP, 2), 64, 0, stream>>>(
        imgF, bevF, img_boxes, bev_boxes, img_s, bev_s);
    gemm_fusedA_relu_kernel<<<dim3(HID/GBN, N_PROP/GBM), 256, 0, stream>>>(
        img_s, bev_s, img_mask, bev_mask, W1, b1, h1, N_PROP, HID, D_FEAT);
    gemm_relu_kernel<<<dim3(HID/GBN, N_PROP/GBM), 256, 0, stream>>>(
        h1, W2, b2, h2, N_PROP, HID, HID, 1);
    heads_kernel<<<N_PROP, 256, 0, stream>>>(h2, Wc, bc, Wo, bo, Wa, ba, anchors,
                                             obj_soft, off, orient, pred, pbev, scores);
    nms_kernel<<<1, 64, 0, stream>>>(pbev, scores, idx);
    gather_kernel<<<1, 128, 0, stream>>>(idx, obj_soft, pred, off, orient,
                                         (float*)d_out);
}

// Round 5
// 785.794 us; speedup vs baseline: 2.3100x; 1.9510x over previous
//
#include <hip/hip_runtime.h>
#include <math.h>

#define N_PROP 1024
#define C_FEAT 32
#define ROI 7
#define SR 6
#define S_GRID 42
#define IMG_H 360
#define IMG_W 1200
#define BEV_H 700
#define BEV_W 800
#define D_FEAT (C_FEAT*ROI*ROI)   // 1568
#define HID 2048
#define NMS_K 100
#define NMS_THR 0.01f

// ---------------- workspace layout (float offsets) ----------------
#define WS_IMG_BOXES 0
#define WS_BEV_BOXES (WS_IMG_BOXES + 4*N_PROP)
#define WS_OBJS      (WS_BEV_BOXES + 4*N_PROP)
#define WS_OFF       (WS_OBJS + 2*N_PROP)
#define WS_ORIENT    (WS_OFF + 10*N_PROP)
#define WS_PRED      (WS_ORIENT + N_PROP)
#define WS_PBEV      (WS_PRED + 6*N_PROP)
#define WS_SCORES    (WS_PBEV + 4*N_PROP)
#define WS_IDX       (WS_SCORES + N_PROP)   // ints (100)
#define WS_A         40960
#define WS_B         (WS_A + N_PROP*HID)
#define WS_C         (WS_B + N_PROP*HID)

// ---------------- K1: project boxes ----------------
__global__ void boxes_kernel(const float* __restrict__ anchors,
                             const float* __restrict__ calib,
                             const int* __restrict__ imshape,
                             float* __restrict__ img_boxes,
                             float* __restrict__ bev_boxes) {
    int n = blockIdx.x * blockDim.x + threadIdx.x;
    if (n >= N_PROP) return;
    float x = anchors[n*6+0], y = anchors[n*6+1], z = anchors[n*6+2];
    float dx = anchors[n*6+3], dy = anchors[n*6+4], dz = anchors[n*6+5];

    bev_boxes[n*4+0] = ((x - dx*0.5f) - (-40.0f)) / 0.1f;
    bev_boxes[n*4+1] = (70.0f - (z + dz*0.5f)) / 0.1f;
    bev_boxes[n*4+2] = ((x + dx*0.5f) - (-40.0f)) / 0.1f;
    bev_boxes[n*4+3] = (70.0f - (z - dz*0.5f)) / 0.1f;

    float P[12];
    #pragma unroll
    for (int i = 0; i < 12; i++) P[i] = calib[i];

    float umin = 1e30f, vmin = 1e30f, umax = -1e30f, vmax = -1e30f;
    #pragma unroll
    for (int k = 0; k < 8; k++) {
        float fsx = (k & 4) ? 1.0f : -1.0f;
        float fsy = (k & 2) ? 1.0f : -1.0f;
        float fsz = (k & 1) ? 1.0f : -1.0f;
        float cx = x + fsx * dx * 0.5f;
        float cy = y + fsy * dy * 0.5f;
        float cz = z + fsz * dz * 0.5f;
        float p0 = P[0]*cx + P[1]*cy + P[2]*cz + P[3];
        float p1 = P[4]*cx + P[5]*cy + P[6]*cz + P[7];
        float p2 = P[8]*cx + P[9]*cy + P[10]*cz + P[11];
        float zz = fmaxf(p2, 0.1f);
        float u = p0 / zz, v = p1 / zz;
        umin = fminf(umin, u); umax = fmaxf(umax, u);
        vmin = fminf(vmin, v); vmax = fmaxf(vmax, v);
    }
    float Hf = (float)imshape[0];
    float Wf = (float)imshape[1];
    img_boxes[n*4+0] = fminf(fmaxf(umin, 0.0f), Wf);
    img_boxes[n*4+1] = fminf(fmaxf(vmin, 0.0f), Hf);
    img_boxes[n*4+2] = fminf(fmaxf(umax, 0.0f), Wf);
    img_boxes[n*4+3] = fminf(fmaxf(vmax, 0.0f), Hf);
}

// ---------------- K2: roi_align, one wave per (channel, box, map) -------------
// R1-proven grid (65536 single-wave blocks, 88% occupancy) + per-py shuffle
// amortization. __launch_bounds__(64,8) hard-caps VGPR at 64 (R2/R3: compiler
// pipelining blew VGPR to 252 -> 10% occupancy -> 4x slower). py loop kept
// rolled so only one 24-load window is in flight.
__global__ __launch_bounds__(64, 8) void roi_map_kernel(
        const float* __restrict__ imgF, const float* __restrict__ bevF,
        const float* __restrict__ img_boxes, const float* __restrict__ bev_boxes,
        float* __restrict__ img_out, float* __restrict__ bev_out) {
    int c = blockIdx.x;      // channel 0..31
    int b = blockIdx.y;      // box 0..1023
    int mapid = blockIdx.z;  // 0=img, 1=bev

    const float* F; const float* boxes; float* outp; int W, H;
    if (mapid == 0) { F = imgF; boxes = img_boxes; outp = img_out; W = IMG_W; H = IMG_H; }
    else            { F = bevF; boxes = bev_boxes; outp = bev_out; W = BEV_W; H = BEV_H; }
    const float* f = F + (size_t)c * W * H;

    int lane = threadIdx.x;
    float bx1 = boxes[b*4+0], by1 = boxes[b*4+1];
    float bx2 = boxes[b*4+2], by2 = boxes[b*4+3];

    __shared__ int   s_row0[S_GRID], s_row1[S_GRID];  // y0*W, y1*W element offsets
    __shared__ float s_wy[S_GRID];

    int x0i = 0, x1i = 0;
    float wx = 0.0f;
    if (lane < S_GRID) {
        float g = ((float)lane + 0.5f) / (float)S_GRID;
        float c1 = bx1 - 0.5f, c2 = bx2 - 0.5f;
        float xs = c1 + g * (c2 - c1);
        float x0f = fminf(fmaxf(floorf(xs), 0.0f), (float)(W-1));
        wx = fminf(fmaxf(xs - x0f, 0.0f), 1.0f);
        x0i = (int)x0f;
        x1i = min(x0i + 1, W - 1);

        float d1 = by1 - 0.5f, d2 = by2 - 0.5f;
        float ys = d1 + g * (d2 - d1);
        float y0f = fminf(fmaxf(floorf(ys), 0.0f), (float)(H-1));
        float wyv = fminf(fmaxf(ys - y0f, 0.0f), 1.0f);
        int y0 = (int)y0f;
        int y1 = min(y0 + 1, H - 1);
        s_row0[lane] = y0 * W;
        s_row1[lane] = y1 * W;
        s_wy[lane] = wyv;
    }
    __syncthreads();

    float* op = outp + (size_t)b * D_FEAT + c * 49;
    #pragma unroll 1
    for (int py = 0; py < ROI; py++) {
        float pl = 0.0f;     // per-lane accumulation over the 6 sub-rows
        #pragma unroll
        for (int sy = 0; sy < SR; sy++) {
            int yi = py * SR + sy;
            int r0 = s_row0[yi], r1 = s_row1[yi];   // LDS broadcast
            float wy = s_wy[yi];
            if (lane < S_GRID) {
                float v00 = f[r0 + x0i], v01 = f[r0 + x1i];
                float v10 = f[r1 + x0i], v11 = f[r1 + x1i];
                float top = fmaf(wx, v01 - v00, v00);
                float bot = fmaf(wx, v11 - v10, v10);
                pl += fmaf(wy, bot - top, top);
            }
        }
        // segmented sum over groups of 6 lanes; valid at lanes 0,6,...,36
        float s = pl;
        #pragma unroll
        for (int k = 1; k < 6; k++) s += __shfl_down(pl, k);
        if (lane < S_GRID && (lane % 6) == 0)
            op[py * ROI + lane / 6] = s;
    }
}

// ---------------- K3: GEMM1 (R1-proven 64x64) with fused A combine ----------
#define GBM 64
#define GBN 64
#define GBK 16
__global__ __launch_bounds__(256) void gemm_fusedA_relu_kernel(
        const float* __restrict__ imgS, const float* __restrict__ bevS,
        const float* __restrict__ img_mask, const float* __restrict__ bev_mask,
        const float* __restrict__ B, const float* __restrict__ bias,
        float* __restrict__ C, int M, int N, int K) {
    __shared__ float As[GBK][GBM + 4];
    __shared__ float Bs[GBK][GBN];
    float m0 = img_mask[0], m1 = bev_mask[0];
    float inv = 1.0f / ((m0 + m1) * 36.0f);
    float w0 = m0 * inv, w1 = m1 * inv;
    int tid = threadIdx.x;
    int tx = tid & 15, ty = tid >> 4;
    int m0i = blockIdx.y * GBM, n0 = blockIdx.x * GBN;
    float acc[4][4] = {};
    int arow = tid >> 2;
    int acg  = (tid & 3) << 2;
    int brow = tid >> 4;
    int bcol = (tid & 15) << 2;

    for (int k0 = 0; k0 < K; k0 += GBK) {
        size_t aidx = (size_t)(m0i + arow) * K + k0 + acg;
        float4 ia = *(const float4*)(imgS + aidx);
        float4 ba = *(const float4*)(bevS + aidx);
        float4 av;
        av.x = w0 * ia.x + w1 * ba.x;
        av.y = w0 * ia.y + w1 * ba.y;
        av.z = w0 * ia.z + w1 * ba.z;
        av.w = w0 * ia.w + w1 * ba.w;
        float4 bv = *(const float4*)(B + (size_t)(k0 + brow) * N + n0 + bcol);
        __syncthreads();
        As[acg+0][arow] = av.x;
        As[acg+1][arow] = av.y;
        As[acg+2][arow] = av.z;
        As[acg+3][arow] = av.w;
        *(float4*)&Bs[brow][bcol] = bv;
        __syncthreads();
        #pragma unroll
        for (int kk = 0; kk < GBK; kk++) {
            float4 a = *(const float4*)&As[kk][ty * 4];
            float4 b = *(const float4*)&Bs[kk][tx * 4];
            float aa[4] = {a.x, a.y, a.z, a.w};
            float bb[4] = {b.x, b.y, b.z, b.w};
            #pragma unroll
            for (int i = 0; i < 4; i++)
                #pragma unroll
                for (int j = 0; j < 4; j++)
                    acc[i][j] += aa[i] * bb[j];
        }
    }
    float4 bv = *(const float4*)(bias + n0 + tx * 4);
    float bb[4] = {bv.x, bv.y, bv.z, bv.w};
    #pragma unroll
    for (int i = 0; i < 4; i++) {
        int m = m0i + ty * 4 + i;
        float4 o;
        o.x = fmaxf(acc[i][0] + bb[0], 0.0f);
        o.y = fmaxf(acc[i][1] + bb[1], 0.0f);
        o.z = fmaxf(acc[i][2] + bb[2], 0.0f);
        o.w = fmaxf(acc[i][3] + bb[3], 0.0f);
        *(float4*)(C + (size_t)m * N + n0 + tx * 4) = o;
    }
}

// ---------------- K4: plain fp32 tiled GEMM (R1-proven), relu ----------------
__global__ __launch_bounds__(256) void gemm_relu_kernel(
        const float* __restrict__ A, const float* __restrict__ B,
        const float* __restrict__ bias, float* __restrict__ C,
        int M, int N, int K, int do_relu) {
    __shared__ float As[GBK][GBM + 4];
    __shared__ float Bs[GBK][GBN];
    int tid = threadIdx.x;
    int tx = tid & 15, ty = tid >> 4;
    int m0 = blockIdx.y * GBM, n0 = blockIdx.x * GBN;
    float acc[4][4] = {};
    int arow = tid >> 2;
    int acg  = (tid & 3) << 2;
    int brow = tid >> 4;
    int bcol = (tid & 15) << 2;

    for (int k0 = 0; k0 < K; k0 += GBK) {
        float4 av = *(const float4*)(A + (size_t)(m0 + arow) * K + k0 + acg);
        float4 bv = *(const float4*)(B + (size_t)(k0 + brow) * N + n0 + bcol);
        __syncthreads();
        As[acg+0][arow] = av.x;
        As[acg+1][arow] = av.y;
        As[acg+2][arow] = av.z;
        As[acg+3][arow] = av.w;
        *(float4*)&Bs[brow][bcol] = bv;
        __syncthreads();
        #pragma unroll
        for (int kk = 0; kk < GBK; kk++) {
            float4 a = *(const float4*)&As[kk][ty * 4];
            float4 b = *(const float4*)&Bs[kk][tx * 4];
            float aa[4] = {a.x, a.y, a.z, a.w};
            float bb[4] = {b.x, b.y, b.z, b.w};
            #pragma unroll
            for (int i = 0; i < 4; i++)
                #pragma unroll
                for (int j = 0; j < 4; j++)
                    acc[i][j] += aa[i] * bb[j];
        }
    }
    float4 bv = *(const float4*)(bias + n0 + tx * 4);
    float bb[4] = {bv.x, bv.y, bv.z, bv.w};
    #pragma unroll
    for (int i = 0; i < 4; i++) {
        int m = m0 + ty * 4 + i;
        float4 o;
        float v0 = acc[i][0] + bb[0];
        float v1 = acc[i][1] + bb[1];
        float v2 = acc[i][2] + bb[2];
        float v3 = acc[i][3] + bb[3];
        if (do_relu) {
            v0 = fmaxf(v0, 0.0f); v1 = fmaxf(v1, 0.0f);
            v2 = fmaxf(v2, 0.0f); v3 = fmaxf(v3, 0.0f);
        }
        o.x = v0; o.y = v1; o.z = v2; o.w = v3;
        *(float4*)(C + (size_t)m * N + n0 + tx * 4) = o;
    }
}

// ---------------- K5: heads (obj/off/ang) + postprocess per row ----------------
__global__ __launch_bounds__(256) void heads_kernel(
        const float* __restrict__ h,
        const float* __restrict__ Wc, const float* __restrict__ bc,
        const float* __restrict__ Wo, const float* __restrict__ bo,
        const float* __restrict__ Wa, const float* __restrict__ ba,
        const float* __restrict__ anchors,
        float* __restrict__ obj_soft, float* __restrict__ off_out,
        float* __restrict__ orient, float* __restrict__ pred,
        float* __restrict__ pbev, float* __restrict__ scores) {
    int row = blockIdx.x;
    const float* hr = h + (size_t)row * HID;
    float acc[14];
    #pragma unroll
    for (int j = 0; j < 14; j++) acc[j] = 0.0f;
    for (int k = threadIdx.x; k < HID; k += 256) {
        float hv = hr[k];
        acc[0]  += hv * Wc[k*2+0];
        acc[1]  += hv * Wc[k*2+1];
        #pragma unroll
        for (int j = 0; j < 10; j++) acc[2+j] += hv * Wo[k*10+j];
        acc[12] += hv * Wa[k*2+0];
        acc[13] += hv * Wa[k*2+1];
    }
    #pragma unroll
    for (int d = 32; d > 0; d >>= 1) {
        #pragma unroll
        for (int j = 0; j < 14; j++) acc[j] += __shfl_down(acc[j], d);
    }
    __shared__ float red[4][14];
    int wid = threadIdx.x >> 6, lane = threadIdx.x & 63;
    if (lane == 0) {
        #pragma unroll
        for (int j = 0; j < 14; j++) red[wid][j] = acc[j];
    }
    __syncthreads();
    if (threadIdx.x == 0) {
        float f[14];
        #pragma unroll
        for (int j = 0; j < 14; j++)
            f[j] = red[0][j] + red[1][j] + red[2][j] + red[3][j];
        float obj0 = f[0] + bc[0], obj1 = f[1] + bc[1];
        float offv[10];
        #pragma unroll
        for (int j = 0; j < 10; j++) offv[j] = f[2+j] + bo[j];
        float ang0 = f[12] + ba[0], ang1 = f[13] + ba[1];
        float mx = fmaxf(obj0, obj1);
        float e0 = expf(obj0 - mx), e1 = expf(obj1 - mx);
        float den = e0 + e1;
        obj_soft[row*2+0] = e0 / den;
        obj_soft[row*2+1] = e1 / den;
        scores[row] = obj1;
        orient[row] = atan2f(ang1, ang0);
        float pa[6];
        #pragma unroll
        for (int j = 0; j < 6; j++) {
            pa[j] = anchors[row*6+j] + offv[j];
            pred[row*6+j] = pa[j];
        }
        #pragma unroll
        for (int j = 0; j < 10; j++) off_out[row*10+j] = offv[j];
        float x = pa[0], z = pa[2], ddx = pa[3], ddz = pa[5];
        pbev[row*4+0] = ((x - ddx*0.5f) - (-40.0f)) / 0.1f;
        pbev[row*4+1] = (70.0f - (z + ddz*0.5f)) / 0.1f;
        pbev[row*4+2] = ((x + ddx*0.5f) - (-40.0f)) / 0.1f;
        pbev[row*4+3] = (70.0f - (z - ddz*0.5f)) / 0.1f;
    }
}

// ---------------- K6: sequential NMS, single wave, fused suppress+argmax -------
__global__ void nms_kernel(const float* __restrict__ boxes,
                           const float* __restrict__ scores_g,
                           int* __restrict__ idx_out) {
    __shared__ float4 sb4[N_PROP];
    __shared__ float  sa[N_PROP];
    int lane = threadIdx.x;   // 64 threads
    float sc[16], x1v[16], y1v[16], x2v[16], y2v[16], ar[16];
    const float4* bp = (const float4*)boxes;
    #pragma unroll
    for (int j = 0; j < 16; j++) {
        int g = lane + 64*j;
        float4 bb = bp[g];
        x1v[j] = bb.x; y1v[j] = bb.y; x2v[j] = bb.z; y2v[j] = bb.w;
        ar[j] = (bb.z - bb.x) * (bb.w - bb.y);
        sc[j] = scores_g[g];
        sb4[g] = bb;
        sa[g] = ar[j];
    }
    // initial per-lane argmax (first-index tie-break: ascending g, strict >)
    float bv = sc[0]; int bi = lane;
    #pragma unroll
    for (int j = 1; j < 16; j++) {
        int g = lane + 64*j;
        if (sc[j] > bv) { bv = sc[j]; bi = g; }
    }
    for (int t = 0; t < NMS_K; t++) {
        #pragma unroll
        for (int d = 1; d < 64; d <<= 1) {
            float ov = __shfl_xor(bv, d);
            int   oi = __shfl_xor(bi, d);
            if (ov > bv || (ov == bv && oi < bi)) { bv = ov; bi = oi; }
        }
        if (lane == 0) idx_out[t] = bi;
        float4 pb = sb4[bi];
        float pa = sa[bi];
        float nbv = -INFINITY; int nbi = lane;
        #pragma unroll
        for (int j = 0; j < 16; j++) {
            int g = lane + 64*j;
            float xx1 = fmaxf(x1v[j], pb.x), yy1 = fmaxf(y1v[j], pb.y);
            float xx2 = fminf(x2v[j], pb.z), yy2 = fminf(y2v[j], pb.w);
            float inter = fmaxf(xx2 - xx1, 0.0f) * fmaxf(yy2 - yy1, 0.0f);
            float iou = inter / (ar[j] + pa - inter + 1e-6f);
            if (iou > NMS_THR || g == bi) sc[j] = -INFINITY;
            if (sc[j] > nbv) { nbv = sc[j]; nbi = g; }
        }
        bv = nbv; bi = nbi;
    }
}

// ---------------- K7: gather outputs ----------------
__global__ void gather_kernel(const int* __restrict__ idx,
                              const float* __restrict__ obj_soft,
                              const float* __restrict__ pred,
                              const float* __restrict__ off,
                              const float* __restrict__ orient,
                              float* __restrict__ out) {
    int i = threadIdx.x;
    if (i < NMS_K) {
        int j = idx[i];
        out[2*i+0] = obj_soft[j*2+0];
        out[2*i+1] = obj_soft[j*2+1];
        #pragma unroll
        for (int t = 0; t < 6; t++) out[200 + 6*i + t] = pred[j*6+t];
        #pragma unroll
        for (int t = 0; t < 10; t++) out[800 + 10*i + t] = off[j*10+t];
        #pragma unroll
        for (int t = 0; t < 6; t++) out[1800 + 7*i + t] = pred[j*6+t];
        out[1800 + 7*i + 6] = 0.0f;
        out[2500 + i] = orient[j];
    }
}

extern "C" void kernel_launch(void* const* d_in, const int* in_sizes, int n_in,
                              void* d_out, int out_size, void* d_ws, size_t ws_size,
                              hipStream_t stream) {
    const float* imgF     = (const float*)d_in[0];
    const float* bevF     = (const float*)d_in[1];
    const float* anchors  = (const float*)d_in[2];
    const float* calib    = (const float*)d_in[3];
    const float* img_mask = (const float*)d_in[5];
    const float* bev_mask = (const float*)d_in[6];
    const float* W1 = (const float*)d_in[7];
    const float* b1 = (const float*)d_in[8];
    const float* W2 = (const float*)d_in[9];
    const float* b2 = (const float*)d_in[10];
    const float* Wc = (const float*)d_in[11];
    const float* bc = (const float*)d_in[12];
    const float* Wo = (const float*)d_in[13];
    const float* bo = (const float*)d_in[14];
    const float* Wa = (const float*)d_in[15];
    const float* ba = (const float*)d_in[16];
    const int* image_shape = (const int*)d_in[17];

    float* ws = (float*)d_ws;
    float* img_boxes = ws + WS_IMG_BOXES;
    float* bev_boxes = ws + WS_BEV_BOXES;
    float* obj_soft  = ws + WS_OBJS;
    float* off       = ws + WS_OFF;
    float* orient    = ws + WS_ORIENT;
    float* pred      = ws + WS_PRED;
    float* pbev      = ws + WS_PBEV;
    float* scores    = ws + WS_SCORES;
    int*   idx       = (int*)(ws + WS_IDX);
    float* img_s     = ws + WS_A;            // region A
    float* bev_s     = ws + WS_B;            // region B
    float* h1        = ws + WS_C;            // region C
    float* h2        = ws + WS_A;            // reuses region A (img_s dead)

    boxes_kernel<<<N_PROP/64, 64, 0, stream>>>(anchors, calib, image_shape,
                                               img_boxes, bev_boxes);
    roi_map_kernel<<<dim3(C_FEAT, N_PROP, 2), 64, 0, stream>>>(
        imgF, bevF, img_boxes, bev_boxes, img_s, bev_s);
    gemm_fusedA_relu_kernel<<<dim3(HID/GBN, N_PROP/GBM), 256, 0, stream>>>(
        img_s, bev_s, img_mask, bev_mask, W1, b1, h1, N_PROP, HID, D_FEAT);
    gemm_relu_kernel<<<dim3(HID/GBN, N_PROP/GBM), 256, 0, stream>>>(
        h1, W2, b2, h2, N_PROP, HID, HID, 1);
    heads_kernel<<<N_PROP, 256, 0, stream>>>(h2, Wc, bc, Wo, bo, Wa, ba, anchors,
                                             obj_soft, off, orient, pred, pbev, scores);
    nms_kernel<<<1, 64, 0, stream>>>(pbev, scores, idx);
    gather_kernel<<<1, 128, 0, stream>>>(idx, obj_soft, pred, off, orient,
                                         (float*)d_out);
}

// Round 6
// 686.208 us; speedup vs baseline: 2.6452x; 1.1451x over previous
//
#include <hip/hip_runtime.h>
#include <math.h>

#define N_PROP 1024
#define C_FEAT 32
#define ROI 7
#define SR 6
#define S_GRID 42
#define IMG_H 360
#define IMG_W 1200
#define BEV_H 700
#define BEV_W 800
#define D_FEAT (C_FEAT*ROI*ROI)   // 1568
#define HID 2048
#define NMS_K 100
#define NMS_THR 0.01f

typedef __attribute__((ext_vector_type(8))) short bf16x8;
typedef __attribute__((ext_vector_type(4))) float f32x4;

// ---------------- workspace layout (float offsets) ----------------
// Peak 4,857,856 floats = 19.4 MB (< 25.3 MB proven).
//   roi:     img_s[R0], bev_s[R1]
//   combine: reads R0,R1 -> fusedHi/Lo (bf16, after R1)
//   gemm1:   reads fused -> h1Hi/Lo (bf16) @ R0 (img_s/bev_s dead)
//   gemm2:   reads h1 -> h2 fp32 @ after h1 (fused dead)
#define WS_IMG_BOXES 0
#define WS_BEV_BOXES (WS_IMG_BOXES + 4*N_PROP)
#define WS_OBJS      (WS_BEV_BOXES + 4*N_PROP)
#define WS_OFF       (WS_OBJS + 2*N_PROP)
#define WS_ORIENT    (WS_OFF + 10*N_PROP)
#define WS_PRED      (WS_ORIENT + N_PROP)
#define WS_PBEV      (WS_PRED + 6*N_PROP)
#define WS_SCORES    (WS_PBEV + 4*N_PROP)
#define WS_IDX       (WS_SCORES + N_PROP)
#define WS_R0        40960
#define WS_R1        (WS_R0 + N_PROP*D_FEAT)            // 40960+1605632
#define WS_FUSED_HI  (WS_R0 + 2*N_PROP*D_FEAT)          // 3252224 (802816 f)
#define WS_FUSED_LO  (WS_FUSED_HI + N_PROP*D_FEAT/2)    // 4055040
#define WS_H1HI      WS_R0                               // 1048576 f (bf16 2M elems)
#define WS_H1LO      (WS_R0 + N_PROP*HID/2)             // 1089536
#define WS_H2        (WS_R0 + N_PROP*HID)               // 2138112 (2097152 f fp32)

__device__ __forceinline__ unsigned int bf16_rtn(float x) {
    unsigned int u = __float_as_uint(x);
    return (u + 0x7FFFu + ((u >> 16) & 1u)) >> 16;
}

// ---------------- K1: project boxes ----------------
__global__ void boxes_kernel(const float* __restrict__ anchors,
                             const float* __restrict__ calib,
                             const int* __restrict__ imshape,
                             float* __restrict__ img_boxes,
                             float* __restrict__ bev_boxes) {
    int n = blockIdx.x * blockDim.x + threadIdx.x;
    if (n >= N_PROP) return;
    float x = anchors[n*6+0], y = anchors[n*6+1], z = anchors[n*6+2];
    float dx = anchors[n*6+3], dy = anchors[n*6+4], dz = anchors[n*6+5];

    bev_boxes[n*4+0] = ((x - dx*0.5f) - (-40.0f)) / 0.1f;
    bev_boxes[n*4+1] = (70.0f - (z + dz*0.5f)) / 0.1f;
    bev_boxes[n*4+2] = ((x + dx*0.5f) - (-40.0f)) / 0.1f;
    bev_boxes[n*4+3] = (70.0f - (z - dz*0.5f)) / 0.1f;

    float P[12];
    #pragma unroll
    for (int i = 0; i < 12; i++) P[i] = calib[i];

    float umin = 1e30f, vmin = 1e30f, umax = -1e30f, vmax = -1e30f;
    #pragma unroll
    for (int k = 0; k < 8; k++) {
        float fsx = (k & 4) ? 1.0f : -1.0f;
        float fsy = (k & 2) ? 1.0f : -1.0f;
        float fsz = (k & 1) ? 1.0f : -1.0f;
        float cx = x + fsx * dx * 0.5f;
        float cy = y + fsy * dy * 0.5f;
        float cz = z + fsz * dz * 0.5f;
        float p0 = P[0]*cx + P[1]*cy + P[2]*cz + P[3];
        float p1 = P[4]*cx + P[5]*cy + P[6]*cz + P[7];
        float p2 = P[8]*cx + P[9]*cy + P[10]*cz + P[11];
        float zz = fmaxf(p2, 0.1f);
        float u = p0 / zz, v = p1 / zz;
        umin = fminf(umin, u); umax = fmaxf(umax, u);
        vmin = fminf(vmin, v); vmax = fmaxf(vmax, v);
    }
    float Hf = (float)imshape[0];
    float Wf = (float)imshape[1];
    img_boxes[n*4+0] = fminf(fmaxf(umin, 0.0f), Wf);
    img_boxes[n*4+1] = fminf(fmaxf(vmin, 0.0f), Hf);
    img_boxes[n*4+2] = fminf(fmaxf(umax, 0.0f), Wf);
    img_boxes[n*4+3] = fminf(fmaxf(vmax, 0.0f), Hf);
}

// ---------------- K2: roi_align (R4-proven: 216us, 16 VGPR, 87% occ) ---------
__global__ __launch_bounds__(64, 8) void roi_map_kernel(
        const float* __restrict__ imgF, const float* __restrict__ bevF,
        const float* __restrict__ img_boxes, const float* __restrict__ bev_boxes,
        float* __restrict__ img_out, float* __restrict__ bev_out) {
    int c = blockIdx.x;
    int b = blockIdx.y;
    int mapid = blockIdx.z;

    const float* F; const float* boxes; float* outp; int W, H;
    if (mapid == 0) { F = imgF; boxes = img_boxes; outp = img_out; W = IMG_W; H = IMG_H; }
    else            { F = bevF; boxes = bev_boxes; outp = bev_out; W = BEV_W; H = BEV_H; }
    const float* f = F + (size_t)c * W * H;

    int lane = threadIdx.x;
    float bx1 = boxes[b*4+0], by1 = boxes[b*4+1];
    float bx2 = boxes[b*4+2], by2 = boxes[b*4+3];

    __shared__ int   s_row0[S_GRID], s_row1[S_GRID];
    __shared__ float s_wy[S_GRID];

    int x0i = 0, x1i = 0;
    float wx = 0.0f;
    if (lane < S_GRID) {
        float g = ((float)lane + 0.5f) / (float)S_GRID;
        float c1 = bx1 - 0.5f, c2 = bx2 - 0.5f;
        float xs = c1 + g * (c2 - c1);
        float x0f = fminf(fmaxf(floorf(xs), 0.0f), (float)(W-1));
        wx = fminf(fmaxf(xs - x0f, 0.0f), 1.0f);
        x0i = (int)x0f;
        x1i = min(x0i + 1, W - 1);

        float d1 = by1 - 0.5f, d2 = by2 - 0.5f;
        float ys = d1 + g * (d2 - d1);
        float y0f = fminf(fmaxf(floorf(ys), 0.0f), (float)(H-1));
        float wyv = fminf(fmaxf(ys - y0f, 0.0f), 1.0f);
        int y0 = (int)y0f;
        int y1 = min(y0 + 1, H - 1);
        s_row0[lane] = y0 * W;
        s_row1[lane] = y1 * W;
        s_wy[lane] = wyv;
    }
    __syncthreads();

    float* op = outp + (size_t)b * D_FEAT + c * 49;
    #pragma unroll 1
    for (int py = 0; py < ROI; py++) {
        float pl = 0.0f;
        #pragma unroll
        for (int sy = 0; sy < SR; sy++) {
            int yi = py * SR + sy;
            int r0 = s_row0[yi], r1 = s_row1[yi];
            float wy = s_wy[yi];
            if (lane < S_GRID) {
                float v00 = f[r0 + x0i], v01 = f[r0 + x1i];
                float v10 = f[r1 + x0i], v11 = f[r1 + x1i];
                float top = fmaf(wx, v01 - v00, v00);
                float bot = fmaf(wx, v11 - v10, v10);
                pl += fmaf(wy, bot - top, top);
            }
        }
        float s = pl;
        #pragma unroll
        for (int k = 1; k < 6; k++) s += __shfl_down(pl, k);
        if (lane < S_GRID && (lane % 6) == 0)
            op[py * ROI + lane / 6] = s;
    }
}

// ---------------- K3: combine masks + split fp32 -> bf16 hi/lo ----------------
__global__ __launch_bounds__(256) void combine_split_kernel(
        const float4* __restrict__ img, const float4* __restrict__ bev,
        const float* __restrict__ img_mask, const float* __restrict__ bev_mask,
        ushort4* __restrict__ outHi, ushort4* __restrict__ outLo, int total4) {
    int i = blockIdx.x * 256 + threadIdx.x;
    if (i >= total4) return;
    float m0 = img_mask[0], m1 = bev_mask[0];
    float inv = 1.0f / ((m0 + m1) * 36.0f);
    float w0 = m0 * inv, w1 = m1 * inv;
    float4 a = img[i], b = bev[i];
    float v[4] = { w0*a.x + w1*b.x, w0*a.y + w1*b.y, w0*a.z + w1*b.z, w0*a.w + w1*b.w };
    ushort4 hv, lv;
    unsigned short* hp = &hv.x;
    unsigned short* lp = &lv.x;
    #pragma unroll
    for (int e = 0; e < 4; e++) {
        unsigned int rh = bf16_rtn(v[e]);
        float lo = v[e] - __uint_as_float(rh << 16);
        hp[e] = (unsigned short)rh;
        lp[e] = (unsigned short)bf16_rtn(lo);
    }
    outHi[i] = hv;
    outLo[i] = lv;
}

// ---------------- K4: bf16x2 MFMA GEMM, C = relu(A@W + bias) ----------------
// A: [M][K] pre-split bf16 hi/lo.  W: [K][2048] fp32, transposed+split into
// LDS on the fly.  Tile 64x128, BK=32, grid 16x16 = 256 blocks (1/CU).
// 3 MFMAs (hh, hl, lh) per tile-pair -> ~fp32 precision in fp32 accum.
// EPI=1: write bf16 hi/lo (h1);  EPI=0: write fp32 (h2).
#define LDK 40   // LDS row stride (shorts); 80B rows keep b128 16B-aligned
template<int EPI>
__global__ __launch_bounds__(256) void gemm_bf16x2_kernel(
        const unsigned short* __restrict__ Ahi, const unsigned short* __restrict__ Alo,
        const float* __restrict__ W, const float* __restrict__ bias, int K,
        unsigned short* __restrict__ outHi, unsigned short* __restrict__ outLo,
        float* __restrict__ outF) {
    __shared__ short AsH[64*LDK], AsL[64*LDK];
    __shared__ short BsH[128*LDK], BsL[128*LDK];

    const int tid = threadIdx.x;
    const int m0 = blockIdx.y * 64, n0 = blockIdx.x * 128;

    // A staging: thread -> one 16B chunk (8 bf16): m = tid>>2, k-chunk = tid&3
    const int am = tid >> 2, ac = tid & 3;
    const uint4* ApH = (const uint4*)(Ahi + (size_t)(m0 + am) * K + ac*8);
    const uint4* ApL = (const uint4*)(Alo + (size_t)(m0 + am) * K + ac*8);
    // B staging: thread -> one n-column, 16 k-rows (coalesced scalar loads)
    const int nn = tid & 127, rbase = (tid >> 7) * 16;
    const float* Bp = W + (size_t)rbase * 2048 + n0 + nn;

    const int lane = tid & 63, wave = tid >> 6;
    const int wm = wave & 1, wn = wave >> 1;
    const int l15 = lane & 15, quad = lane >> 4;

    f32x4 acc[2][4];
    #pragma unroll
    for (int i = 0; i < 2; i++)
        #pragma unroll
        for (int j = 0; j < 4; j++)
            acc[i][j] = (f32x4){0.f, 0.f, 0.f, 0.f};

    const int nK = K >> 5;
    // prefetch kstep 0
    uint4 aHr = ApH[0];        // element offset k0=0 (in 8-bf16 units handled by ptr)
    uint4 aLr = ApL[0];
    float bReg[16];
    #pragma unroll
    for (int j = 0; j < 16; j++) bReg[j] = Bp[(size_t)j * 2048];

    for (int ks = 0; ks < nK; ks++) {
        __syncthreads();
        // ---- write LDS from prefetched regs ----
        *(uint4*)&AsH[am*LDK + ac*8] = aHr;
        *(uint4*)&AsL[am*LDK + ac*8] = aLr;
        {
            unsigned short hv[16], lv[16];
            #pragma unroll
            for (int j = 0; j < 16; j++) {
                unsigned int rh = bf16_rtn(bReg[j]);
                float lo = bReg[j] - __uint_as_float(rh << 16);
                hv[j] = (unsigned short)rh;
                lv[j] = (unsigned short)bf16_rtn(lo);
            }
            *(uint4*)&BsH[nn*LDK + rbase + 0] = *(uint4*)&hv[0];
            *(uint4*)&BsH[nn*LDK + rbase + 8] = *(uint4*)&hv[8];
            *(uint4*)&BsL[nn*LDK + rbase + 0] = *(uint4*)&lv[0];
            *(uint4*)&BsL[nn*LDK + rbase + 8] = *(uint4*)&lv[8];
        }
        __syncthreads();
        // ---- prefetch next kstep (overlaps MFMA below) ----
        if (ks + 1 < nK) {
            int k0n = (ks + 1) * 32;
            aHr = ApH[k0n >> 3];     // uint4 ptr: 8 bf16 per step
            aLr = ApL[k0n >> 3];
            #pragma unroll
            for (int j = 0; j < 16; j++) bReg[j] = Bp[(size_t)(k0n + j) * 2048];
        }
        // ---- fragments + MFMA ----
        const short* aBH = AsH + (wm*32 + l15)*LDK + quad*8;
        const short* aBL = AsL + (wm*32 + l15)*LDK + quad*8;
        const short* bBH = BsH + (wn*64 + l15)*LDK + quad*8;
        const short* bBL = BsL + (wn*64 + l15)*LDK + quad*8;
        bf16x8 aH0 = *(const bf16x8*)(aBH);
        bf16x8 aH1 = *(const bf16x8*)(aBH + 16*LDK);
        bf16x8 aL0 = *(const bf16x8*)(aBL);
        bf16x8 aL1 = *(const bf16x8*)(aBL + 16*LDK);
        #pragma unroll
        for (int nt = 0; nt < 4; nt++) {
            bf16x8 bH = *(const bf16x8*)(bBH + nt*16*LDK);
            bf16x8 bL = *(const bf16x8*)(bBL + nt*16*LDK);
            acc[0][nt] = __builtin_amdgcn_mfma_f32_16x16x32_bf16(aH0, bH, acc[0][nt], 0, 0, 0);
            acc[0][nt] = __builtin_amdgcn_mfma_f32_16x16x32_bf16(aH0, bL, acc[0][nt], 0, 0, 0);
            acc[0][nt] = __builtin_amdgcn_mfma_f32_16x16x32_bf16(aL0, bH, acc[0][nt], 0, 0, 0);
            acc[1][nt] = __builtin_amdgcn_mfma_f32_16x16x32_bf16(aH1, bH, acc[1][nt], 0, 0, 0);
            acc[1][nt] = __builtin_amdgcn_mfma_f32_16x16x32_bf16(aH1, bL, acc[1][nt], 0, 0, 0);
            acc[1][nt] = __builtin_amdgcn_mfma_f32_16x16x32_bf16(aL1, bH, acc[1][nt], 0, 0, 0);
        }
    }

    // ---- epilogue: D[row=quad*4+reg][col=l15] per 16x16 tile ----
    #pragma unroll
    for (int mt = 0; mt < 2; mt++) {
        #pragma unroll
        for (int nt = 0; nt < 4; nt++) {
            int n = n0 + wn*64 + nt*16 + l15;
            float bv = bias[n];
            #pragma unroll
            for (int reg = 0; reg < 4; reg++) {
                int m = m0 + wm*32 + mt*16 + quad*4 + reg;
                float v = fmaxf(acc[mt][nt][reg] + bv, 0.0f);
                if (EPI == 1) {
                    unsigned int rh = bf16_rtn(v);
                    float lo = v - __uint_as_float(rh << 16);
                    outHi[(size_t)m * 2048 + n] = (unsigned short)rh;
                    outLo[(size_t)m * 2048 + n] = (unsigned short)bf16_rtn(lo);
                } else {
                    outF[(size_t)m * 2048 + n] = v;
                }
            }
        }
    }
}

// ---------------- K5: heads (obj/off/ang) + postprocess per row ----------------
__global__ __launch_bounds__(256) void heads_kernel(
        const float* __restrict__ h,
        const float* __restrict__ Wc, const float* __restrict__ bc,
        const float* __restrict__ Wo, const float* __restrict__ bo,
        const float* __restrict__ Wa, const float* __restrict__ ba,
        const float* __restrict__ anchors,
        float* __restrict__ obj_soft, float* __restrict__ off_out,
        float* __restrict__ orient, float* __restrict__ pred,
        float* __restrict__ pbev, float* __restrict__ scores) {
    int row = blockIdx.x;
    const float* hr = h + (size_t)row * HID;
    float acc[14];
    #pragma unroll
    for (int j = 0; j < 14; j++) acc[j] = 0.0f;
    for (int k = threadIdx.x; k < HID; k += 256) {
        float hv = hr[k];
        acc[0]  += hv * Wc[k*2+0];
        acc[1]  += hv * Wc[k*2+1];
        #pragma unroll
        for (int j = 0; j < 10; j++) acc[2+j] += hv * Wo[k*10+j];
        acc[12] += hv * Wa[k*2+0];
        acc[13] += hv * Wa[k*2+1];
    }
    #pragma unroll
    for (int d = 32; d > 0; d >>= 1) {
        #pragma unroll
        for (int j = 0; j < 14; j++) acc[j] += __shfl_down(acc[j], d);
    }
    __shared__ float red[4][14];
    int wid = threadIdx.x >> 6, lane = threadIdx.x & 63;
    if (lane == 0) {
        #pragma unroll
        for (int j = 0; j < 14; j++) red[wid][j] = acc[j];
    }
    __syncthreads();
    if (threadIdx.x == 0) {
        float f[14];
        #pragma unroll
        for (int j = 0; j < 14; j++)
            f[j] = red[0][j] + red[1][j] + red[2][j] + red[3][j];
        float obj0 = f[0] + bc[0], obj1 = f[1] + bc[1];
        float offv[10];
        #pragma unroll
        for (int j = 0; j < 10; j++) offv[j] = f[2+j] + bo[j];
        float ang0 = f[12] + ba[0], ang1 = f[13] + ba[1];
        float mx = fmaxf(obj0, obj1);
        float e0 = expf(obj0 - mx), e1 = expf(obj1 - mx);
        float den = e0 + e1;
        obj_soft[row*2+0] = e0 / den;
        obj_soft[row*2+1] = e1 / den;
        scores[row] = obj1;
        orient[row] = atan2f(ang1, ang0);
        float pa[6];
        #pragma unroll
        for (int j = 0; j < 6; j++) {
            pa[j] = anchors[row*6+j] + offv[j];
            pred[row*6+j] = pa[j];
        }
        #pragma unroll
        for (int j = 0; j < 10; j++) off_out[row*10+j] = offv[j];
        float x = pa[0], z = pa[2], ddx = pa[3], ddz = pa[5];
        pbev[row*4+0] = ((x - ddx*0.5f) - (-40.0f)) / 0.1f;
        pbev[row*4+1] = (70.0f - (z + ddz*0.5f)) / 0.1f;
        pbev[row*4+2] = ((x + ddx*0.5f) - (-40.0f)) / 0.1f;
        pbev[row*4+3] = (70.0f - (z - ddz*0.5f)) / 0.1f;
    }
}

// ---------------- K6: sequential NMS, single wave, fused suppress+argmax -------
__global__ void nms_kernel(const float* __restrict__ boxes,
                           const float* __restrict__ scores_g,
                           int* __restrict__ idx_out) {
    __shared__ float4 sb4[N_PROP];
    __shared__ float  sa[N_PROP];
    int lane = threadIdx.x;
    float sc[16], x1v[16], y1v[16], x2v[16], y2v[16], ar[16];
    const float4* bp = (const float4*)boxes;
    #pragma unroll
    for (int j = 0; j < 16; j++) {
        int g = lane + 64*j;
        float4 bb = bp[g];
        x1v[j] = bb.x; y1v[j] = bb.y; x2v[j] = bb.z; y2v[j] = bb.w;
        ar[j] = (bb.z - bb.x) * (bb.w - bb.y);
        sc[j] = scores_g[g];
        sb4[g] = bb;
        sa[g] = ar[j];
    }
    float bv = sc[0]; int bi = lane;
    #pragma unroll
    for (int j = 1; j < 16; j++) {
        int g = lane + 64*j;
        if (sc[j] > bv) { bv = sc[j]; bi = g; }
    }
    for (int t = 0; t < NMS_K; t++) {
        #pragma unroll
        for (int d = 1; d < 64; d <<= 1) {
            float ov = __shfl_xor(bv, d);
            int   oi = __shfl_xor(bi, d);
            if (ov > bv || (ov == bv && oi < bi)) { bv = ov; bi = oi; }
        }
        if (lane == 0) idx_out[t] = bi;
        float4 pb = sb4[bi];
        float pa = sa[bi];
        float nbv = -INFINITY; int nbi = lane;
        #pragma unroll
        for (int j = 0; j < 16; j++) {
            int g = lane + 64*j;
            float xx1 = fmaxf(x1v[j], pb.x), yy1 = fmaxf(y1v[j], pb.y);
            float xx2 = fminf(x2v[j], pb.z), yy2 = fminf(y2v[j], pb.w);
            float inter = fmaxf(xx2 - xx1, 0.0f) * fmaxf(yy2 - yy1, 0.0f);
            float iou = inter / (ar[j] + pa - inter + 1e-6f);
            if (iou > NMS_THR || g == bi) sc[j] = -INFINITY;
            if (sc[j] > nbv) { nbv = sc[j]; nbi = g; }
        }
        bv = nbv; bi = nbi;
    }
}

// ---------------- K7: gather outputs ----------------
__global__ void gather_kernel(const int* __restrict__ idx,
                              const float* __restrict__ obj_soft,
                              const float* __restrict__ pred,
                              const float* __restrict__ off,
                              const float* __restrict__ orient,
                              float* __restrict__ out) {
    int i = threadIdx.x;
    if (i < NMS_K) {
        int j = idx[i];
        out[2*i+0] = obj_soft[j*2+0];
        out[2*i+1] = obj_soft[j*2+1];
        #pragma unroll
        for (int t = 0; t < 6; t++) out[200 + 6*i + t] = pred[j*6+t];
        #pragma unroll
        for (int t = 0; t < 10; t++) out[800 + 10*i + t] = off[j*10+t];
        #pragma unroll
        for (int t = 0; t < 6; t++) out[1800 + 7*i + t] = pred[j*6+t];
        out[1800 + 7*i + 6] = 0.0f;
        out[2500 + i] = orient[j];
    }
}

extern "C" void kernel_launch(void* const* d_in, const int* in_sizes, int n_in,
                              void* d_out, int out_size, void* d_ws, size_t ws_size,
                              hipStream_t stream) {
    const float* imgF     = (const float*)d_in[0];
    const float* bevF     = (const float*)d_in[1];
    const float* anchors  = (const float*)d_in[2];
    const float* calib    = (const float*)d_in[3];
    const float* img_mask = (const float*)d_in[5];
    const float* bev_mask = (const float*)d_in[6];
    const float* W1 = (const float*)d_in[7];
    const float* b1 = (const float*)d_in[8];
    const float* W2 = (const float*)d_in[9];
    const float* b2 = (const float*)d_in[10];
    const float* Wc = (const float*)d_in[11];
    const float* bc = (const float*)d_in[12];
    const float* Wo = (const float*)d_in[13];
    const float* bo = (const float*)d_in[14];
    const float* Wa = (const float*)d_in[15];
    const float* ba = (const float*)d_in[16];
    const int* image_shape = (const int*)d_in[17];

    float* ws = (float*)d_ws;
    float* img_boxes = ws + WS_IMG_BOXES;
    float* bev_boxes = ws + WS_BEV_BOXES;
    float* obj_soft  = ws + WS_OBJS;
    float* off       = ws + WS_OFF;
    float* orient    = ws + WS_ORIENT;
    float* pred      = ws + WS_PRED;
    float* pbev      = ws + WS_PBEV;
    float* scores    = ws + WS_SCORES;
    int*   idx       = (int*)(ws + WS_IDX);
    float* img_s     = ws + WS_R0;
    float* bev_s     = ws + WS_R1;
    unsigned short* fusedHi = (unsigned short*)(ws + WS_FUSED_HI);
    unsigned short* fusedLo = (unsigned short*)(ws + WS_FUSED_LO);
    unsigned short* h1Hi    = (unsigned short*)(ws + WS_H1HI);
    unsigned short* h1Lo    = (unsigned short*)(ws + WS_H1LO);
    float* h2        = ws + WS_H2;

    boxes_kernel<<<N_PROP/64, 64, 0, stream>>>(anchors, calib, image_shape,
                                               img_boxes, bev_boxes);
    roi_map_kernel<<<dim3(C_FEAT, N_PROP, 2), 64, 0, stream>>>(
        imgF, bevF, img_boxes, bev_boxes, img_s, bev_s);
    combine_split_kernel<<<(N_PROP*D_FEAT/4 + 255)/256, 256, 0, stream>>>(
        (const float4*)img_s, (const float4*)bev_s, img_mask, bev_mask,
        (ushort4*)fusedHi, (ushort4*)fusedLo, N_PROP*D_FEAT/4);
    gemm_bf16x2_kernel<1><<<dim3(16, 16), 256, 0, stream>>>(
        fusedHi, fusedLo, W1, b1, D_FEAT, h1Hi, h1Lo, nullptr);
    gemm_bf16x2_kernel<0><<<dim3(16, 16), 256, 0, stream>>>(
        h1Hi, h1Lo, W2, b2, HID, nullptr, nullptr, h2);
    heads_kernel<<<N_PROP, 256, 0, stream>>>(h2, Wc, bc, Wo, bo, Wa, ba, anchors,
                                             obj_soft, off, orient, pred, pbev, scores);
    nms_kernel<<<1, 64, 0, stream>>>(pbev, scores, idx);
    gather_kernel<<<1, 128, 0, stream>>>(idx, obj_soft, pred, off, orient,
                                         (float*)d_out);
}